// Round 2
// baseline (255.365 us; speedup 1.0000x reference)
//
#include <hip/hip_runtime.h>

typedef float v2f __attribute__((ext_vector_type(2)));

#define HH 1024
#define WW 1024
#define NB 4
#define NC 3
#define BC 12   // NB*NC
#define N1 255
#define N2 127
#define N3 63
#define N4 31
#define EPS 1e-5f

// ---------------- workspace layout (float offsets) ----------------
constexpr size_t S8_OFF  = 0;
constexpr size_t S8_SZ   = 4ull * BC * N1 * N1;   // raw sums g,s,gg,gs @255^2
constexpr size_t CV16_OFF = S8_OFF + S8_SZ;       // cov,var @127^2
constexpr size_t CV16_SZ  = 2ull * BC * N2 * N2;
constexpr size_t CV32_OFF = CV16_OFF + CV16_SZ;
constexpr size_t CV32_SZ  = 2ull * BC * N3 * N3;
constexpr size_t CV64_OFF = CV32_OFF + CV32_SZ;
constexpr size_t CV64_SZ  = 2ull * BC * N4 * N4;
constexpr size_t A_OFF    = CV64_OFF + CV64_SZ;   // A @ [B,3,255,255]
constexpr size_t A_SZ     = (size_t)NB * NC * N1 * N1;
constexpr size_t BB_OFF   = A_OFF + A_SZ;         // bb @ [B,3,255,255]

// ---------------- kernel 1: 8x8 stride-4 box sums via LDS column sums ----------
// grid: BC*128 blocks; each block computes 2 output rows (i0=2b, i0+1) for one
// bc-image. Phase 1: 256 threads x 4 cols accumulate 4-row partial col sums
// (3 groups of 4 rows from the 12-row strip); phase 2: horizontal 8-sums.
__global__ __launch_bounds__(256) void base_kernel(
    const float* __restrict__ guide, const float* __restrict__ src,
    float* __restrict__ S8)
{
    __shared__ float smem[8][WW];  // [rowsel*4 + q][col], q: g,s,gg,gs

    int b  = blockIdx.x % 128;
    int bc = blockIdx.x / 128;
    int t  = threadIdx.x;          // cols 4t..4t+3

    const float* gbase = guide + (size_t)bc * HH * WW + 4 * t;
    const float* sbase = src   + (size_t)bc * HH * WW + 4 * t;

    float pg[3][4], ps[3][4], pgg[3][4], pgs[3][4];
#pragma unroll
    for (int grp = 0; grp < 3; ++grp)
#pragma unroll
        for (int k = 0; k < 4; ++k) {
            pg[grp][k] = 0.f; ps[grp][k] = 0.f;
            pgg[grp][k] = 0.f; pgs[grp][k] = 0.f;
        }

#pragma unroll
    for (int grp = 0; grp < 3; ++grp) {
#pragma unroll
        for (int r = 0; r < 4; ++r) {
            int row = 8 * b + 4 * grp + r;
            if (row < HH) {   // wave-uniform; false only in last strip, grp 2
                float4 g4 = *(const float4*)(gbase + (size_t)row * WW);
                float4 s4 = *(const float4*)(sbase + (size_t)row * WW);
                float ge[4] = {g4.x, g4.y, g4.z, g4.w};
                float se[4] = {s4.x, s4.y, s4.z, s4.w};
#pragma unroll
                for (int k = 0; k < 4; ++k) {
                    pg[grp][k]  += ge[k];
                    ps[grp][k]  += se[k];
                    pgg[grp][k] += ge[k] * ge[k];
                    pgs[grp][k] += ge[k] * se[k];
                }
            }
        }
    }

#pragma unroll
    for (int k = 0; k < 4; ++k) {
        int c = 4 * t + k;
        smem[0][c] = pg[0][k]  + pg[1][k];    // output row i0: input rows 8b..8b+7
        smem[1][c] = ps[0][k]  + ps[1][k];
        smem[2][c] = pgg[0][k] + pgg[1][k];
        smem[3][c] = pgs[0][k] + pgs[1][k];
        smem[4][c] = pg[1][k]  + pg[2][k];    // output row i0+1: rows 8b+4..8b+11
        smem[5][c] = ps[1][k]  + ps[2][k];
        smem[6][c] = pgg[1][k] + pgg[2][k];
        smem[7][c] = pgs[1][k] + pgs[2][k];
    }
    __syncthreads();

    if (t < N1) {
        size_t qs   = (size_t)BC * N1 * N1;
        size_t base = (size_t)bc * N1 * N1;
#pragma unroll
        for (int rsel = 0; rsel < 2; ++rsel) {
            int i = 2 * b + rsel;
            if (i < N1) {
#pragma unroll
                for (int q = 0; q < 4; ++q) {
                    const float* arr = smem[4 * rsel + q];
                    float4 a4 = *(const float4*)(arr + 4 * t);
                    float4 b4 = *(const float4*)(arr + 4 * t + 4);
                    float v = (a4.x + a4.y) + (a4.z + a4.w) +
                              (b4.x + b4.y) + (b4.z + b4.w);
                    S8[(size_t)q * qs + base + (size_t)i * N1 + t] = v;
                }
            }
        }
    }
}

// ---------------- kernel 2: all pyramid stats directly from S8 -----------------
// r=16/32/64 windows are exact unions of 2x2 / 4x4 / 8x8 r=8 windows on the
// stride-4 grid (S8 index offsets 2k). One launch for all three levels.
__global__ __launch_bounds__(256) void pyr_all(
    const float* __restrict__ S8, float* __restrict__ CV16,
    float* __restrict__ CV32, float* __restrict__ CV64)
{
    const int n2t = BC * N2 * N2, n3t = BC * N3 * N3, n4t = BC * N4 * N4;
    int idx = blockIdx.x * 256 + threadIdx.x;

    float* CV; int nout, cnt; float invN; int rem;
    if (idx < n2t)              { CV = CV16; nout = N2; cnt = 2; invN = 1.f / 256.f;  rem = idx; }
    else if (idx < n2t + n3t)   { CV = CV32; nout = N3; cnt = 4; invN = 1.f / 1024.f; rem = idx - n2t; }
    else if (idx < n2t + n3t + n4t) { CV = CV64; nout = N4; cnt = 8; invN = 1.f / 4096.f; rem = idx - n2t - n3t; }
    else return;

    int j  = rem % nout;
    int tt = rem / nout;
    int i  = tt % nout;
    int bc = tt / nout;

    size_t qs = (size_t)BC * N1 * N1;
    const float* P = S8 + (size_t)bc * N1 * N1;
    int p0 = cnt * i, q0 = cnt * j;

    float s0 = 0.f, s1 = 0.f, s2 = 0.f, s3 = 0.f;
    for (int ky = 0; ky < cnt; ++ky) {
        size_t roff = (size_t)(p0 + 2 * ky) * N1 + q0;
        for (int kx = 0; kx < cnt; ++kx) {
            size_t o = roff + 2 * kx;
            s0 += P[0 * qs + o];
            s1 += P[1 * qs + o];
            s2 += P[2 * qs + o];
            s3 += P[3 * qs + o];
        }
    }

    size_t sOut = (size_t)BC * nout * nout;
    size_t o    = (size_t)bc * nout * nout + (size_t)i * nout + j;
    float mx = s0 * invN, my = s1 * invN;
    CV[o]        = s3 * invN - mx * my;  // cov
    CV[sOut + o] = s2 * invN - mx * mx;  // var
}

// ---------------- kernel 3: fused feature-gather + packed-fp32 MLP -------------
__global__ __launch_bounds__(128) void mlp_kernel(
    const float* __restrict__ S8,
    const float* __restrict__ CV16, const float* __restrict__ CV32,
    const float* __restrict__ CV64,
    const float* __restrict__ w1, const float* __restrict__ g1,
    const float* __restrict__ b1, const float* __restrict__ rm1,
    const float* __restrict__ rv1,
    const float* __restrict__ w2, const float* __restrict__ g2,
    const float* __restrict__ b2, const float* __restrict__ rm2,
    const float* __restrict__ rv2,
    const float* __restrict__ w3,
    float* __restrict__ A, float* __restrict__ Bb)
{
    __shared__ float sw1[48 * 24], sw2[48 * 48], sw3[3 * 48];
    __shared__ float inv1[48], bia1[48], inv2[48], bia2[48];
    int t = threadIdx.x;
    for (int k = t; k < 48 * 24; k += 128) sw1[k] = w1[k];
    for (int k = t; k < 48 * 48; k += 128) sw2[k] = w2[k];
    for (int k = t; k < 3 * 48; k += 128) sw3[k] = w3[k];
    if (t < 48) {
        float iv = g1[t] * rsqrtf(rv1[t] + EPS);
        inv1[t] = iv; bia1[t] = b1[t] - rm1[t] * iv;
        float iv2 = g2[t] * rsqrtf(rv2[t] + EPS);
        inv2[t] = iv2; bia2[t] = b2[t] - rm2[t] * iv2;
    }
    __syncthreads();

    int idx = blockIdx.x * 128 + t;
    if (idx >= NB * N1 * N1) return;
    int ox = idx % N1;
    int r  = idx / N1;
    int oy = r % N1;
    int b  = r / N1;

    float feats[24], mx1[3], my1[3];

    // level 1 (r=8): stats inline from raw sums
    size_t s8q = (size_t)BC * N1 * N1;
#pragma unroll
    for (int c = 0; c < 3; ++c) {
        size_t o = (size_t)(b * 3 + c) * N1 * N1 + (size_t)oy * N1 + ox;
        float sg = S8[o], ss = S8[s8q + o], sgg = S8[2 * s8q + o], sgs = S8[3 * s8q + o];
        float mx = sg * (1.f / 64.f), my = ss * (1.f / 64.f);
        mx1[c] = mx; my1[c] = my;
        feats[c]     = sgs * (1.f / 64.f) - mx * my;
        feats[3 + c] = sgg * (1.f / 64.f) - mx * mx;
    }

    // levels 2..4: bilinear (align_corners) gather of cov/var
    const float* CVs[3] = {CV16, CV32, CV64};
    const int nins[3]   = {N2, N3, N4};
    const float scales[3] = {(float)(126.0 / 254.0), (float)(62.0 / 254.0),
                             (float)(30.0 / 254.0)};
#pragma unroll
    for (int l = 0; l < 3; ++l) {
        const float* CV = CVs[l];
        int nin = nins[l];
        float sc = scales[l];
        float py = (float)oy * sc;
        int   i0 = min(max((int)floorf(py), 0), nin - 2);
        float wy = py - (float)i0;
        float px = (float)ox * sc;
        int   j0 = min(max((int)floorf(px), 0), nin - 2);
        float wx = px - (float)j0;
        size_t cvq = (size_t)BC * nin * nin;
        int fo = 6 + 6 * l;
#pragma unroll
        for (int c = 0; c < 3; ++c) {
            size_t bix = (size_t)(b * 3 + c) * nin * nin;
            size_t o00 = bix + (size_t)i0 * nin + j0;
            float c00 = CV[o00], c01 = CV[o00 + 1];
            float c10 = CV[o00 + nin], c11 = CV[o00 + nin + 1];
            feats[fo + c] = (c00 * (1.f - wy) + c10 * wy) * (1.f - wx) +
                            (c01 * (1.f - wy) + c11 * wy) * wx;
            float v00 = CV[cvq + o00], v01 = CV[cvq + o00 + 1];
            float v10 = CV[cvq + o00 + nin], v11 = CV[cvq + o00 + nin + 1];
            feats[fo + 3 + c] = (v00 * (1.f - wy) + v10 * wy) * (1.f - wx) +
                                (v01 * (1.f - wy) + v11 * wy) * wx;
        }
    }

    v2f f2[12];
#pragma unroll
    for (int k = 0; k < 12; ++k) { f2[k][0] = feats[2 * k]; f2[k][1] = feats[2 * k + 1]; }

    // MLP 24->48->48->3 with packed-fp32 dot products (v_pk_fma_f32)
    v2f h1v[24];
#pragma unroll
    for (int o = 0; o < 48; ++o) {
        const v2f* wrow = (const v2f*)(&sw1[o * 24]);
        v2f acc = {0.f, 0.f};
#pragma unroll
        for (int c = 0; c < 12; ++c) acc += wrow[c] * f2[c];
        float v = fmaxf((acc[0] + acc[1]) * inv1[o] + bia1[o], 0.f);
        h1v[o >> 1][o & 1] = v;
    }
    v2f h2v[24];
#pragma unroll
    for (int o = 0; o < 48; ++o) {
        const v2f* wrow = (const v2f*)(&sw2[o * 48]);
        v2f acc = {0.f, 0.f};
#pragma unroll
        for (int c = 0; c < 24; ++c) acc += wrow[c] * h1v[c];
        float v = fmaxf((acc[0] + acc[1]) * inv2[o] + bia2[o], 0.f);
        h2v[o >> 1][o & 1] = v;
    }
#pragma unroll
    for (int c = 0; c < 3; ++c) {
        const v2f* wrow = (const v2f*)(&sw3[c * 48]);
        v2f acc = {0.f, 0.f};
#pragma unroll
        for (int k = 0; k < 24; ++k) acc += wrow[k] * h2v[k];
        float a = acc[0] + acc[1];
        size_t o = (size_t)(b * 3 + c) * N1 * N1 + (size_t)oy * N1 + ox;
        A[o]  = a;
        Bb[o] = my1[c] - a * mx1[c];
    }
}

// ---------------- kernel 4: fused upsample + apply ----------------
__global__ __launch_bounds__(256) void final_kernel(
    const float* __restrict__ guide, const float* __restrict__ A,
    const float* __restrict__ Bb, float* __restrict__ out)
{
    __shared__ float aH[N1 + 1], bH[N1 + 1];
    int blk = blockIdx.x;
    int bc  = blk / HH;
    int h   = blk % HH;

    const float scale = (float)(254.0 / 1023.0);
    float py = (float)h * scale;
    int   i0 = min(max((int)floorf(py), 0), N1 - 2);
    float wy = py - (float)i0;

    int t = threadIdx.x;
    if (t < N1) {
        size_t base = (size_t)bc * N1 * N1 + (size_t)i0 * N1 + t;
        aH[t] = A[base] * (1.f - wy) + A[base + N1] * wy;
        bH[t] = Bb[base] * (1.f - wy) + Bb[base + N1] * wy;
    }
    __syncthreads();

    const float* gp = guide + (size_t)bc * HH * WW + (size_t)h * WW;
    float*       op = out   + (size_t)bc * HH * WW + (size_t)h * WW;

    float4 g4 = *(const float4*)(gp + 4 * t);
    float ge[4] = {g4.x, g4.y, g4.z, g4.w};
    float oe[4];
#pragma unroll
    for (int k = 0; k < 4; ++k) {
        int w = 4 * t + k;
        float px = (float)w * scale;
        int   j0 = min(max((int)floorf(px), 0), N1 - 2);
        float wx = px - (float)j0;
        float a   = aH[j0] * (1.f - wx) + aH[j0 + 1] * wx;
        float bbv = bH[j0] * (1.f - wx) + bH[j0 + 1] * wx;
        oe[k] = a * ge[k] + bbv;
    }
    float4 o4; o4.x = oe[0]; o4.y = oe[1]; o4.z = oe[2]; o4.w = oe[3];
    *(float4*)(op + 4 * t) = o4;
}

// ---------------- launch ----------------
extern "C" void kernel_launch(void* const* d_in, const int* in_sizes, int n_in,
                              void* d_out, int out_size, void* d_ws, size_t ws_size,
                              hipStream_t stream)
{
    const float* guide = (const float*)d_in[0];
    const float* src   = (const float*)d_in[1];
    const float* w1    = (const float*)d_in[2];
    const float* g1    = (const float*)d_in[3];
    const float* b1    = (const float*)d_in[4];
    const float* rm1   = (const float*)d_in[5];
    const float* rv1   = (const float*)d_in[6];
    const float* w2    = (const float*)d_in[7];
    const float* g2    = (const float*)d_in[8];
    const float* b2    = (const float*)d_in[9];
    const float* rm2   = (const float*)d_in[10];
    const float* rv2   = (const float*)d_in[11];
    const float* w3    = (const float*)d_in[12];
    float*       out   = (float*)d_out;

    float* ws   = (float*)d_ws;
    float* S8   = ws + S8_OFF;
    float* CV16 = ws + CV16_OFF;
    float* CV32 = ws + CV32_OFF;
    float* CV64 = ws + CV64_OFF;
    float* Abuf = ws + A_OFF;
    float* Bbuf = ws + BB_OFF;

    // 1. base 8x8/s4 box sums (LDS column-sum formulation)
    base_kernel<<<BC * 128, 256, 0, stream>>>(guide, src, S8);

    // 2. all pyramid stats in one launch
    {
        int total = BC * (N2 * N2 + N3 * N3 + N4 * N4);
        pyr_all<<<(total + 255) / 256, 256, 0, stream>>>(S8, CV16, CV32, CV64);
    }

    // 3. fused gather + MLP -> A, bb @255^2
    {
        int total = NB * N1 * N1;
        mlp_kernel<<<(total + 127) / 128, 128, 0, stream>>>(
            S8, CV16, CV32, CV64, w1, g1, b1, rm1, rv1, w2, g2, b2, rm2, rv2, w3,
            Abuf, Bbuf);
    }

    // 4. fused upsample + apply
    final_kernel<<<BC * HH, 256, 0, stream>>>(guide, Abuf, Bbuf, out);
}

// Round 3
// 238.013 us; speedup vs baseline: 1.0729x; 1.0729x over previous
//
#include <hip/hip_runtime.h>

typedef float v2f __attribute__((ext_vector_type(2)));

#define HH 1024
#define WW 1024
#define NB 4
#define NC 3
#define BC 12   // NB*NC
#define N1 255
#define N2 127
#define N3 63
#define N4 31
#define EPS 1e-5f
#define NPIX (NB * N1 * N1)   // 260100
#define NPAIR (NPIX / 2)      // 130050

// ---------------- workspace layout (float offsets) ----------------
// S8: AoS float4 {g,s,gg,gs} per site [bc][255][255]
constexpr size_t S8_OFF = 0;
constexpr size_t S8_SZ  = 4ull * BC * N1 * N1;
// CV*: interleaved v2f {cov,var} per site
constexpr size_t CV16_OFF = S8_OFF + S8_SZ;
constexpr size_t CV16_SZ  = 2ull * BC * N2 * N2;
constexpr size_t CV32_OFF = CV16_OFF + CV16_SZ;
constexpr size_t CV32_SZ  = 2ull * BC * N3 * N3;
constexpr size_t CV64_OFF = CV32_OFF + CV32_SZ;
constexpr size_t CV64_SZ  = 2ull * BC * N4 * N4;
// AB: interleaved v2f {A, b} per site [b*3+c][255][255]
constexpr size_t AB_OFF = CV64_OFF + CV64_SZ;

// ---------------- kernel 1: 8x8 stride-4 box sums via LDS column sums ----------
__global__ __launch_bounds__(256) void base_kernel(
    const float* __restrict__ guide, const float* __restrict__ src,
    float4* __restrict__ S8q)
{
    __shared__ float smem[8][WW];  // [rowsel*4 + q][col], q: g,s,gg,gs

    int b  = blockIdx.x % 128;
    int bc = blockIdx.x / 128;
    int t  = threadIdx.x;          // cols 4t..4t+3

    const float* gbase = guide + (size_t)bc * HH * WW + 4 * t;
    const float* sbase = src   + (size_t)bc * HH * WW + 4 * t;

    float pg[3][4], ps[3][4], pgg[3][4], pgs[3][4];
#pragma unroll
    for (int grp = 0; grp < 3; ++grp)
#pragma unroll
        for (int k = 0; k < 4; ++k) {
            pg[grp][k] = 0.f; ps[grp][k] = 0.f;
            pgg[grp][k] = 0.f; pgs[grp][k] = 0.f;
        }

#pragma unroll
    for (int grp = 0; grp < 3; ++grp) {
#pragma unroll
        for (int r = 0; r < 4; ++r) {
            int row = 8 * b + 4 * grp + r;
            if (row < HH) {   // wave-uniform; false only for b=127, grp 2
                float4 g4 = *(const float4*)(gbase + (size_t)row * WW);
                float4 s4 = *(const float4*)(sbase + (size_t)row * WW);
                float ge[4] = {g4.x, g4.y, g4.z, g4.w};
                float se[4] = {s4.x, s4.y, s4.z, s4.w};
#pragma unroll
                for (int k = 0; k < 4; ++k) {
                    pg[grp][k]  += ge[k];
                    ps[grp][k]  += se[k];
                    pgg[grp][k] += ge[k] * ge[k];
                    pgs[grp][k] += ge[k] * se[k];
                }
            }
        }
    }

#pragma unroll
    for (int k = 0; k < 4; ++k) {
        int c = 4 * t + k;
        smem[0][c] = pg[0][k]  + pg[1][k];
        smem[1][c] = ps[0][k]  + ps[1][k];
        smem[2][c] = pgg[0][k] + pgg[1][k];
        smem[3][c] = pgs[0][k] + pgs[1][k];
        smem[4][c] = pg[1][k]  + pg[2][k];
        smem[5][c] = ps[1][k]  + ps[2][k];
        smem[6][c] = pgg[1][k] + pgg[2][k];
        smem[7][c] = pgs[1][k] + pgs[2][k];
    }
    __syncthreads();

    if (t < N1) {
        size_t plane = (size_t)bc * N1 * N1;
#pragma unroll
        for (int rsel = 0; rsel < 2; ++rsel) {
            int i = 2 * b + rsel;
            if (i < N1) {
                float qv[4];
#pragma unroll
                for (int q = 0; q < 4; ++q) {
                    const float* arr = smem[4 * rsel + q];
                    float4 a4 = *(const float4*)(arr + 4 * t);
                    float4 b4 = *(const float4*)(arr + 4 * t + 4);
                    qv[q] = (a4.x + a4.y) + (a4.z + a4.w) +
                            (b4.x + b4.y) + (b4.z + b4.w);
                }
                float4 o4; o4.x = qv[0]; o4.y = qv[1]; o4.z = qv[2]; o4.w = qv[3];
                S8q[plane + (size_t)i * N1 + t] = o4;
            }
        }
    }
}

// ---------------- kernel 2: all pyramid stats directly from S8 -----------------
__global__ __launch_bounds__(256) void pyr_all(
    const float4* __restrict__ S8q, v2f* __restrict__ CV16,
    v2f* __restrict__ CV32, v2f* __restrict__ CV64)
{
    const int n2t = BC * N2 * N2, n3t = BC * N3 * N3, n4t = BC * N4 * N4;
    int idx = blockIdx.x * 256 + threadIdx.x;

    v2f* CV; int nout, cnt; float invN; int rem;
    if (idx < n2t)              { CV = CV16; nout = N2; cnt = 2; invN = 1.f / 256.f;  rem = idx; }
    else if (idx < n2t + n3t)   { CV = CV32; nout = N3; cnt = 4; invN = 1.f / 1024.f; rem = idx - n2t; }
    else if (idx < n2t + n3t + n4t) { CV = CV64; nout = N4; cnt = 8; invN = 1.f / 4096.f; rem = idx - n2t - n3t; }
    else return;

    int j  = rem % nout;
    int tt = rem / nout;
    int i  = tt % nout;
    int bc = tt / nout;

    const float4* P = S8q + (size_t)bc * N1 * N1;
    int p0 = cnt * i, q0 = cnt * j;

    float s0 = 0.f, s1 = 0.f, s2 = 0.f, s3 = 0.f;
    for (int ky = 0; ky < cnt; ++ky) {
        size_t roff = (size_t)(p0 + 2 * ky) * N1 + q0;
        for (int kx = 0; kx < cnt; ++kx) {
            float4 q4 = P[roff + 2 * kx];
            s0 += q4.x; s1 += q4.y; s2 += q4.z; s3 += q4.w;
        }
    }

    size_t o = (size_t)bc * nout * nout + (size_t)i * nout + j;
    float mx = s0 * invN, my = s1 * invN;
    v2f cv; cv[0] = s3 * invN - mx * my; cv[1] = s2 * invN - mx * mx;
    CV[o] = cv;
}

// ---------------- kernel 3: pixel-pair packed MLP ------------------------------
// Each thread handles 2 pixels packed into v2f lanes; weights read once per
// pair as float4 (4 channels) -> LDS bytes/pixel cut 4x vs per-pixel scheme.
__global__ __launch_bounds__(256) void mlp_kernel(
    const float4* __restrict__ S8q,
    const v2f* __restrict__ CV16, const v2f* __restrict__ CV32,
    const v2f* __restrict__ CV64,
    const float* __restrict__ w1, const float* __restrict__ g1,
    const float* __restrict__ b1, const float* __restrict__ rm1,
    const float* __restrict__ rv1,
    const float* __restrict__ w2, const float* __restrict__ g2,
    const float* __restrict__ b2, const float* __restrict__ rm2,
    const float* __restrict__ rv2,
    const float* __restrict__ w3,
    v2f* __restrict__ AB)
{
    __shared__ float4 sw1q[288], sw2q[576], sw3q[36];
    __shared__ float inv1[48], bia1[48], inv2[48], bia2[48];
    int t = threadIdx.x;
    {
        const float4* w1q = (const float4*)w1;
        const float4* w2q = (const float4*)w2;
        const float4* w3q = (const float4*)w3;
        for (int k = t; k < 288; k += 256) sw1q[k] = w1q[k];
        for (int k = t; k < 576; k += 256) sw2q[k] = w2q[k];
        if (t < 36) sw3q[t] = w3q[t];
        if (t < 48) {
            float iv = g1[t] * rsqrtf(rv1[t] + EPS);
            inv1[t] = iv; bia1[t] = b1[t] - rm1[t] * iv;
            float iv2 = g2[t] * rsqrtf(rv2[t] + EPS);
            inv2[t] = iv2; bia2[t] = b2[t] - rm2[t] * iv2;
        }
    }
    __syncthreads();

    int gid = blockIdx.x * 256 + t;
    if (gid >= NPAIR) return;

    float fA[24], fB[24], mxs[2][3], mys[2][3];
    int bs[2], inpl[2];

    const float scales[3] = {(float)(126.0 / 254.0), (float)(62.0 / 254.0),
                             (float)(30.0 / 254.0)};

#pragma unroll
    for (int s = 0; s < 2; ++s) {
        int pidx = 2 * gid + s;
        int ox = pidx % N1;
        int r  = pidx / N1;
        int oy = r % N1;
        int b  = r / N1;
        bs[s] = b; inpl[s] = oy * N1 + ox;
        float* f = s ? fB : fA;

        // level 1 (r=8) from raw sums
#pragma unroll
        for (int c = 0; c < 3; ++c) {
            float4 q4 = S8q[(size_t)(b * 3 + c) * N1 * N1 + (size_t)oy * N1 + ox];
            float mx = q4.x * (1.f / 64.f), my = q4.y * (1.f / 64.f);
            mxs[s][c] = mx; mys[s][c] = my;
            f[c]     = q4.w * (1.f / 64.f) - mx * my;
            f[3 + c] = q4.z * (1.f / 64.f) - mx * mx;
        }

        // levels 2..4: bilinear gather of {cov,var} pairs
        const v2f* CVs[3] = {CV16, CV32, CV64};
        const int nins[3] = {N2, N3, N4};
#pragma unroll
        for (int l = 0; l < 3; ++l) {
            const v2f* CV = CVs[l];
            int nin = nins[l];
            float sc = scales[l];
            float py = (float)oy * sc;
            int   i0 = min(max((int)floorf(py), 0), nin - 2);
            float wy = py - (float)i0;
            float px = (float)ox * sc;
            int   j0 = min(max((int)floorf(px), 0), nin - 2);
            float wx = px - (float)j0;
            int fo = 6 + 6 * l;
#pragma unroll
            for (int c = 0; c < 3; ++c) {
                size_t o00 = (size_t)(b * 3 + c) * nin * nin + (size_t)i0 * nin + j0;
                v2f c00 = CV[o00], c01 = CV[o00 + 1];
                v2f c10 = CV[o00 + nin], c11 = CV[o00 + nin + 1];
                v2f res = (c00 * (1.f - wy) + c10 * wy) * (1.f - wx) +
                          (c01 * (1.f - wy) + c11 * wy) * wx;
                f[fo + c]     = res[0];
                f[fo + 3 + c] = res[1];
            }
        }
    }

    // pack features over pixel pair
    v2f f2[24];
#pragma unroll
    for (int c = 0; c < 24; ++c) { f2[c][0] = fA[c]; f2[c][1] = fB[c]; }

    // MLP 24->48->48->3; v2f lanes = 2 pixels, v_pk_fma with splat weights
    v2f h1[48];
#pragma unroll
    for (int o = 0; o < 48; ++o) {
        const float4* wr = &sw1q[o * 6];
        v2f acc = {0.f, 0.f};
#pragma unroll
        for (int k = 0; k < 6; ++k) {
            float4 wq = wr[k];
            acc += (v2f){wq.x, wq.x} * f2[4 * k + 0];
            acc += (v2f){wq.y, wq.y} * f2[4 * k + 1];
            acc += (v2f){wq.z, wq.z} * f2[4 * k + 2];
            acc += (v2f){wq.w, wq.w} * f2[4 * k + 3];
        }
        float iv = inv1[o], bb = bia1[o];
        v2f h; h[0] = fmaxf(acc[0] * iv + bb, 0.f); h[1] = fmaxf(acc[1] * iv + bb, 0.f);
        h1[o] = h;
    }
    v2f h2[48];
#pragma unroll
    for (int o = 0; o < 48; ++o) {
        const float4* wr = &sw2q[o * 12];
        v2f acc = {0.f, 0.f};
#pragma unroll
        for (int k = 0; k < 12; ++k) {
            float4 wq = wr[k];
            acc += (v2f){wq.x, wq.x} * h1[4 * k + 0];
            acc += (v2f){wq.y, wq.y} * h1[4 * k + 1];
            acc += (v2f){wq.z, wq.z} * h1[4 * k + 2];
            acc += (v2f){wq.w, wq.w} * h1[4 * k + 3];
        }
        float iv = inv2[o], bb = bia2[o];
        v2f h; h[0] = fmaxf(acc[0] * iv + bb, 0.f); h[1] = fmaxf(acc[1] * iv + bb, 0.f);
        h2[o] = h;
    }
#pragma unroll
    for (int c = 0; c < 3; ++c) {
        const float4* wr = &sw3q[c * 12];
        v2f acc = {0.f, 0.f};
#pragma unroll
        for (int k = 0; k < 12; ++k) {
            float4 wq = wr[k];
            acc += (v2f){wq.x, wq.x} * h2[4 * k + 0];
            acc += (v2f){wq.y, wq.y} * h2[4 * k + 1];
            acc += (v2f){wq.z, wq.z} * h2[4 * k + 2];
            acc += (v2f){wq.w, wq.w} * h2[4 * k + 3];
        }
        // subpixel A: acc[0], subpixel B: acc[1]
        v2f outA; outA[0] = acc[0]; outA[1] = mys[0][c] - acc[0] * mxs[0][c];
        v2f outB; outB[0] = acc[1]; outB[1] = mys[1][c] - acc[1] * mxs[1][c];
        AB[(size_t)(bs[0] * 3 + c) * N1 * N1 + inpl[0]] = outA;
        AB[(size_t)(bs[1] * 3 + c) * N1 * N1 + inpl[1]] = outB;
    }
}

// ---------------- kernel 4: fused upsample + apply ----------------
__global__ __launch_bounds__(256) void final_kernel(
    const float* __restrict__ guide, const v2f* __restrict__ AB,
    float* __restrict__ out)
{
    __shared__ v2f abH[N1 + 1];
    int blk = blockIdx.x;
    int bc  = blk / HH;
    int h   = blk % HH;

    const float scale = (float)(254.0 / 1023.0);
    float py = (float)h * scale;
    int   i0 = min(max((int)floorf(py), 0), N1 - 2);
    float wy = py - (float)i0;

    int t = threadIdx.x;
    if (t < N1) {
        size_t base = (size_t)bc * N1 * N1 + (size_t)i0 * N1 + t;
        v2f p0 = AB[base], p1 = AB[base + N1];
        abH[t] = p0 * (1.f - wy) + p1 * wy;
    }
    __syncthreads();

    const float* gp = guide + (size_t)bc * HH * WW + (size_t)h * WW;
    float*       op = out   + (size_t)bc * HH * WW + (size_t)h * WW;

    float4 g4 = *(const float4*)(gp + 4 * t);
    float ge[4] = {g4.x, g4.y, g4.z, g4.w};
    float oe[4];
#pragma unroll
    for (int k = 0; k < 4; ++k) {
        int w = 4 * t + k;
        float px = (float)w * scale;
        int   j0 = min(max((int)floorf(px), 0), N1 - 2);
        float wx = px - (float)j0;
        v2f ab = abH[j0] * (1.f - wx) + abH[j0 + 1] * wx;
        oe[k] = ab[0] * ge[k] + ab[1];
    }
    float4 o4; o4.x = oe[0]; o4.y = oe[1]; o4.z = oe[2]; o4.w = oe[3];
    *(float4*)(op + 4 * t) = o4;
}

// ---------------- launch ----------------
extern "C" void kernel_launch(void* const* d_in, const int* in_sizes, int n_in,
                              void* d_out, int out_size, void* d_ws, size_t ws_size,
                              hipStream_t stream)
{
    const float* guide = (const float*)d_in[0];
    const float* src   = (const float*)d_in[1];
    const float* w1    = (const float*)d_in[2];
    const float* g1    = (const float*)d_in[3];
    const float* b1    = (const float*)d_in[4];
    const float* rm1   = (const float*)d_in[5];
    const float* rv1   = (const float*)d_in[6];
    const float* w2    = (const float*)d_in[7];
    const float* g2    = (const float*)d_in[8];
    const float* b2    = (const float*)d_in[9];
    const float* rm2   = (const float*)d_in[10];
    const float* rv2   = (const float*)d_in[11];
    const float* w3    = (const float*)d_in[12];
    float*       out   = (float*)d_out;

    float* ws    = (float*)d_ws;
    float4* S8q  = (float4*)(ws + S8_OFF);
    v2f*   CV16  = (v2f*)(ws + CV16_OFF);
    v2f*   CV32  = (v2f*)(ws + CV32_OFF);
    v2f*   CV64  = (v2f*)(ws + CV64_OFF);
    v2f*   AB    = (v2f*)(ws + AB_OFF);

    base_kernel<<<BC * 128, 256, 0, stream>>>(guide, src, S8q);

    {
        int total = BC * (N2 * N2 + N3 * N3 + N4 * N4);
        pyr_all<<<(total + 255) / 256, 256, 0, stream>>>(S8q, CV16, CV32, CV64);
    }

    mlp_kernel<<<(NPAIR + 255) / 256, 256, 0, stream>>>(
        S8q, CV16, CV32, CV64, w1, g1, b1, rm1, rv1, w2, g2, b2, rm2, rv2, w3, AB);

    final_kernel<<<BC * HH, 256, 0, stream>>>(guide, AB, out);
}